// Round 2
// baseline (802.204 us; speedup 1.0000x reference)
//
#include <hip/hip_runtime.h>
#include <hip/hip_bf16.h>
#include <stdint.h>

#define D_ 1024
#define H_ 16
#define DH_ 64
#define S_ 2048
#define B_ 16
static constexpr float SCALE = 0.125f;  // 1/sqrt(64)

typedef __bf16 bf16_t;
typedef __bf16 bf16x8 __attribute__((ext_vector_type(8)));
typedef __bf16 bf16x4 __attribute__((ext_vector_type(4)));
typedef float  f32x4  __attribute__((ext_vector_type(4)));

// ---------------------------------------------------------------------------
// dtype detect: if inputs are f32, bf16-interpretation of the low 16 bits of
// each word has a random exponent -> many |x|>~2^10 elements. Real bf16 data
// (~N(0,0.02)) has none. flag=1 -> f32 inputs, flag=0 -> bf16 inputs.
// ---------------------------------------------------------------------------
__global__ void detect_dtype(const uint32_t* __restrict__ w, int* __restrict__ flag) {
  __shared__ int cnt;
  if (threadIdx.x == 0) cnt = 0;
  __syncthreads();
  uint32_t x = w[threadIdx.x];  // 256 words = 512 bf16-candidates
  int big = 0;
#pragma unroll
  for (int h = 0; h < 2; ++h) {
    uint32_t e = (x >> (7 + 16 * h)) & 0xFF;
    if (e >= 0x89) big++;  // |x| >= ~1024, or inf/nan
  }
  if (big) atomicAdd(&cnt, big);
  __syncthreads();
  if (threadIdx.x == 0) *flag = (cnt > 16) ? 1 : 0;
}

// ---------------------------------------------------------------------------
// 1024x1024 transpose with optional f32->bf16 convert: dst[n][k] = src[k][n]
// ---------------------------------------------------------------------------
__global__ __launch_bounds__(256)
void transpose1024_f(const void* __restrict__ src, bf16_t* __restrict__ dst,
                     const int* __restrict__ flag) {
  __shared__ bf16_t t[64][65];
  const bool isf32 = (*flag != 0);
  const int n0 = blockIdx.x * 64, k0 = blockIdx.y * 64;
  const int r = threadIdx.x >> 4, c4 = (threadIdx.x & 15) * 4;
#pragma unroll
  for (int p = 0; p < 4; ++p) {
    int row = p * 16 + r;
    bf16x4 v;
    if (isf32) {
      f32x4 f = *(const f32x4*)((const float*)src + (size_t)(k0 + row) * 1024 + n0 + c4);
#pragma unroll
      for (int i = 0; i < 4; ++i) v[i] = (bf16_t)f[i];
    } else {
      v = *(const bf16x4*)((const bf16_t*)src + (size_t)(k0 + row) * 1024 + n0 + c4);
    }
#pragma unroll
    for (int i = 0; i < 4; ++i) t[row][c4 + i] = v[i];
  }
  __syncthreads();
#pragma unroll
  for (int p = 0; p < 4; ++p) {
    int row = p * 16 + r;  // n within tile
    bf16x4 v;
#pragma unroll
    for (int i = 0; i < 4; ++i) v[i] = t[c4 + i][row];
    *(bf16x4*)&dst[(size_t)(n0 + row) * 1024 + k0 + c4] = v;
  }
}

// [1024][16] -> [16][1024], optional convert
__global__ __launch_bounds__(256)
void transpose_small_f(const void* __restrict__ src, bf16_t* __restrict__ dst,
                       const int* __restrict__ flag) {
  const bool isf32 = (*flag != 0);
  int k = blockIdx.x * 256 + threadIdx.x;
  if (k < 1024) {
#pragma unroll
    for (int h = 0; h < H_; ++h) {
      float v = isf32 ? ((const float*)src)[k * H_ + h]
                      : (float)((const bf16_t*)src)[k * H_ + h];
      dst[h * 1024 + k] = (bf16_t)v;
    }
  }
}

// biases + mask -> bf16 copies in ws
__global__ __launch_bounds__(256)
void conv_misc(const void* bq, const void* bk, const void* bt,
               const void* bqa, const void* bka, const void* mask,
               bf16_t* obq, bf16_t* obk, bf16_t* obt,
               bf16_t* obqa, bf16_t* obka, bf16_t* omask,
               const int* __restrict__ flag) {
  const bool isf32 = (*flag != 0);
  int i = blockIdx.x * 256 + threadIdx.x;
  const void* src; bf16_t* dst; int off;
  if      (i < 1024)  { src = bq;   dst = obq;   off = i; }
  else if (i < 2048)  { src = bk;   dst = obk;   off = i - 1024; }
  else if (i < 3072)  { src = bt;   dst = obt;   off = i - 2048; }
  else if (i < 3088)  { src = bqa;  dst = obqa;  off = i - 3072; }
  else if (i < 3104)  { src = bka;  dst = obka;  off = i - 3088; }
  else if (i < 35872) { src = mask; dst = omask; off = i - 3104; }
  else return;
  float v = isf32 ? ((const float*)src)[off] : (float)((const bf16_t*)src)[off];
  dst[off] = (bf16_t)v;
}

// ---------------------------------------------------------------------------
// GEMM: C[M][1024] = A[M][1024] @ BT[1024][1024]^T + bias (+epilogue)
// MODE 0: C = A@B + bias                      (mixed_q)
// MODE 1: C = (A@B + bias) * pscale[b][col]   (mixed_qk fused)
// MODE 2: C = A@B + bias + resid              (final out, dtype per flag)
// AEXT=1: A is an external input (dtype per flag). AEXT=0: A is ws bf16.
// 128x128 tile, 4 waves (2x2), BK=32, reg-staged LDS (ds_write_b128).
// ---------------------------------------------------------------------------
template <int MODE, int AEXT>
__global__ __launch_bounds__(256, 2)
void gemm_bt(const void* __restrict__ Asrc, const bf16_t* __restrict__ BT,
             const bf16_t* __restrict__ bias, void* __restrict__ Cout,
             const float* __restrict__ pscale, const bf16_t* __restrict__ resid,
             const int* __restrict__ flag) {
  constexpr int K = 1024, N = 1024;
  __shared__ __align__(16) bf16_t lA[128 * 32];
  __shared__ __align__(16) bf16_t lB[128 * 32];
  const bool f32mode = (*flag != 0);
  const bool af32 = AEXT && f32mode;
  const int tid = threadIdx.x;
  const int lane = tid & 63, wid = tid >> 6;
  const int wr = wid >> 1, wc = wid & 1;
  const int m0 = blockIdx.y * 128;
  const int n0 = blockIdx.x * 128;
  const int ar = lane & 15;        // fragment row/col
  const int ak = (lane >> 4) * 8;  // fragment k offset

  f32x4 acc[4][4] = {};

  for (int k0 = 0; k0 < K; k0 += 32) {
#pragma unroll
    for (int j = 0; j < 2; ++j) {
      int c = j * 256 + tid;              // chunk 0..511 (8 elems each)
      int row = c >> 2, kc = (c & 3) * 8;
      bf16x8 va;
      if (af32) {
        const float* ga = (const float*)Asrc + (size_t)(m0 + row) * K + k0 + kc;
        f32x4 f0 = *(const f32x4*)ga;
        f32x4 f1 = *(const f32x4*)(ga + 4);
#pragma unroll
        for (int i = 0; i < 4; ++i) { va[i] = (bf16_t)f0[i]; va[4 + i] = (bf16_t)f1[i]; }
      } else {
        va = *(const bf16x8*)((const bf16_t*)Asrc + (size_t)(m0 + row) * K + k0 + kc);
      }
      bf16x8 vb = *(const bf16x8*)&BT[(size_t)(n0 + row) * K + k0 + kc];
      *(bf16x8*)&lA[row * 32 + kc] = va;
      *(bf16x8*)&lB[row * 32 + kc] = vb;
    }
    __syncthreads();
    bf16x8 af[4], bg[4];
#pragma unroll
    for (int m = 0; m < 4; ++m)
      af[m] = *(const bf16x8*)&lA[(wr * 64 + m * 16 + ar) * 32 + ak];
#pragma unroll
    for (int n = 0; n < 4; ++n)
      bg[n] = *(const bf16x8*)&lB[(wc * 64 + n * 16 + ar) * 32 + ak];
#pragma unroll
    for (int m = 0; m < 4; ++m)
#pragma unroll
      for (int n = 0; n < 4; ++n)
        acc[m][n] = __builtin_amdgcn_mfma_f32_16x16x32_bf16(af[m], bg[n], acc[m][n], 0, 0, 0);
    __syncthreads();
  }

  const int b = m0 / S_;
#pragma unroll
  for (int m = 0; m < 4; ++m) {
#pragma unroll
    for (int n = 0; n < 4; ++n) {
      const int col = n0 + wc * 64 + n * 16 + (lane & 15);
      const int row_base = m0 + wr * 64 + m * 16 + (lane >> 4) * 4;
      const float bcol = (float)bias[col];
      const float sc = (MODE == 1) ? pscale[b * D_ + col] : 1.0f;
#pragma unroll
      for (int j = 0; j < 4; ++j) {
        const int row = row_base + j;
        float v = acc[m][n][j] + bcol;
        if (MODE == 1) v *= sc;
        if (MODE == 2) v += (float)resid[(size_t)row * N + col];
        if (MODE == 2 && f32mode) ((float*)Cout)[(size_t)row * N + col] = v;
        else                      ((bf16_t*)Cout)[(size_t)row * N + col] = (bf16_t)v;
      }
    }
  }
}

// ---------------------------------------------------------------------------
// scores[b*H+h][s] = (X[b,s,:] . WaT[h,:] + ba[h]) * SCALE + mask[b][s]
// X, WaT, ba, mask all ws bf16. MFMA skinny GEMM (N=16), A direct from global.
// ---------------------------------------------------------------------------
__global__ __launch_bounds__(256)
void score_kernel(const bf16_t* __restrict__ X, const bf16_t* __restrict__ WaT,
                  const bf16_t* __restrict__ ba, const bf16_t* __restrict__ mask,
                  float* __restrict__ scores) {
  const int lane = threadIdx.x & 63, wid = threadIdx.x >> 6;
  const int m0 = blockIdx.x * 64 + wid * 16;  // global row = b*S + s
  const int ar = lane & 15, ak = (lane >> 4) * 8;
  f32x4 acc = {};
  for (int k0 = 0; k0 < D_; k0 += 32) {
    bf16x8 a = *(const bf16x8*)&X[(size_t)(m0 + ar) * D_ + k0 + ak];
    bf16x8 b = *(const bf16x8*)&WaT[(size_t)ar * D_ + k0 + ak];
    acc = __builtin_amdgcn_mfma_f32_16x16x32_bf16(a, b, acc, 0, 0, 0);
  }
  const int h = lane & 15;
  const int srow = m0 + (lane >> 4) * 4;
  const int bb = srow / S_;
  const int s0 = srow - bb * S_;
  const float bah = (float)ba[h];
  f32x4 outv;
#pragma unroll
  for (int j = 0; j < 4; ++j)
    outv[j] = (acc[j] + bah) * SCALE + (float)mask[(size_t)bb * S_ + s0 + j];
  *(f32x4*)&scores[((size_t)(bb * H_ + h)) * S_ + s0] = outv;
}

// ---------------------------------------------------------------------------
// per (b,h): softmax over scores row; pooled[b][h*64+d] = sum_s w[s]*X[b,s,h*64+d]
// ---------------------------------------------------------------------------
__global__ __launch_bounds__(256)
void softmax_pool(const float* __restrict__ scores, const bf16_t* __restrict__ X,
                  float* __restrict__ pooled) {
  __shared__ float w[S_];
  __shared__ float red[4][64];
  __shared__ float rA[4], rB[4];
  const int tid = threadIdx.x, lane = tid & 63, wid = tid >> 6;
  const int bh = blockIdx.x, b = bh >> 4, h = bh & 15;
  const float* srow = scores + (size_t)bh * S_;

  float mx = -1e30f;
  for (int i = tid; i < S_; i += 256) { float v = srow[i]; w[i] = v; mx = fmaxf(mx, v); }
#pragma unroll
  for (int o = 32; o; o >>= 1) mx = fmaxf(mx, __shfl_xor(mx, o));
  if (lane == 0) rA[wid] = mx;
  __syncthreads();
  mx = fmaxf(fmaxf(rA[0], rA[1]), fmaxf(rA[2], rA[3]));

  float sum = 0.f;
  for (int i = tid; i < S_; i += 256) { float p = __expf(w[i] - mx); w[i] = p; sum += p; }
#pragma unroll
  for (int o = 32; o; o >>= 1) sum += __shfl_xor(sum, o);
  if (lane == 0) rB[wid] = sum;
  __syncthreads();  // also orders w[] writes before pooling reads
  sum = rB[0] + rB[1] + rB[2] + rB[3];
  const float inv = 1.0f / sum;

  float accv = 0.f;
  const bf16_t* Xb = X + (size_t)b * S_ * D_ + h * DH_ + lane;  // lane = d
  for (int s = wid; s < S_; s += 4) accv += w[s] * (float)Xb[(size_t)s * D_];
  red[wid][lane] = accv;
  __syncthreads();
  if (tid < 64) {
    float r = (red[0][tid] + red[1][tid] + red[2][tid] + red[3][tid]) * inv;
    pooled[(size_t)b * D_ + h * DH_ + tid] = r;
  }
}

// ---------------------------------------------------------------------------
// weighted[b,s,d] = mq[b,s,d] * pk[b][d]  (into dead mqk buffer)
// ---------------------------------------------------------------------------
__global__ __launch_bounds__(256)
void weighted_kernel(const bf16_t* __restrict__ mq, const float* __restrict__ pk,
                     bf16_t* __restrict__ out) {
  size_t idx = ((size_t)blockIdx.x * 256 + threadIdx.x) * 8;
  int d0 = (int)(idx & (D_ - 1));
  int b = (int)(idx >> 21);  // S_*D_ = 2^21
  bf16x8 v = *(const bf16x8*)&mq[idx];
  const float* pkb = pk + (size_t)b * D_ + d0;
  bf16x8 o;
#pragma unroll
  for (int i = 0; i < 8; ++i) o[i] = (bf16_t)((float)v[i] * pkb[i]);
  *(bf16x8*)&out[idx] = o;
}

// ---------------------------------------------------------------------------
extern "C" void kernel_launch(void* const* d_in, const int* in_sizes, int n_in,
                              void* d_out, int out_size, void* d_ws, size_t ws_size,
                              hipStream_t stream) {
  const void* hs   = d_in[0];
  const void* mask = d_in[1];
  const void* Wq   = d_in[2];
  const void* bq   = d_in[3];
  const void* Wqa  = d_in[4];
  const void* bqa  = d_in[5];
  const void* Wk   = d_in[6];
  const void* bk   = d_in[7];
  const void* Wka  = d_in[8];
  const void* bka  = d_in[9];
  const void* Wt   = d_in[10];
  const void* bt   = d_in[11];

  char* ws = (char*)d_ws;
  int*    flag  = (int*)ws;
  float*  pq    = (float*)(ws + (64u << 10));
  float*  pk    = (float*)(ws + (128u << 10));
  bf16_t* bqc   = (bf16_t*)(ws + (192u << 10));
  bf16_t* bkc   = (bf16_t*)(ws + (192u << 10) + 4096);
  bf16_t* btc   = (bf16_t*)(ws + (192u << 10) + 8192);
  bf16_t* bqac  = (bf16_t*)(ws + (192u << 10) + 12288);
  bf16_t* bkac  = (bf16_t*)(ws + (192u << 10) + 12352);
  bf16_t* maskc = (bf16_t*)(ws + (256u << 10));                 // 64 KB
  bf16_t* WqaT  = (bf16_t*)(ws + (1u << 20));                   // 32 KB
  bf16_t* WkaT  = (bf16_t*)(ws + (1u << 20) + 32768);
  bf16_t* WqT   = (bf16_t*)(ws + (2u << 20));                   // 2 MB
  bf16_t* WkT   = (bf16_t*)(ws + (4u << 20));
  bf16_t* WtT   = (bf16_t*)(ws + (6u << 20));
  bf16_t* mq    = (bf16_t*)(ws + (8u << 20));                   // 64 MB
  bf16_t* mqk   = (bf16_t*)(ws + (8u << 20) + ((size_t)64 << 20));
  float* scores = (float*)(ws + (8u << 20) + ((size_t)128 << 20)); // 2 MB

  detect_dtype<<<1, 256, 0, stream>>>((const uint32_t*)Wq, flag);

  conv_misc<<<141, 256, 0, stream>>>(bq, bk, bt, bqa, bka, mask,
                                     bqc, bkc, btc, bqac, bkac, maskc, flag);
  transpose1024_f<<<dim3(16, 16), 256, 0, stream>>>(Wq, WqT, flag);
  transpose1024_f<<<dim3(16, 16), 256, 0, stream>>>(Wk, WkT, flag);
  transpose1024_f<<<dim3(16, 16), 256, 0, stream>>>(Wt, WtT, flag);
  transpose_small_f<<<4, 256, 0, stream>>>(Wqa, WqaT, flag);
  transpose_small_f<<<4, 256, 0, stream>>>(Wka, WkaT, flag);

  // mixed_q = hs @ Wq + bq
  gemm_bt<0, 1><<<dim3(8, 256), 256, 0, stream>>>(hs, WqT, bqc, mq, nullptr, nullptr, flag);

  score_kernel<<<512, 256, 0, stream>>>(mq, WqaT, bqac, maskc, scores);
  softmax_pool<<<256, 256, 0, stream>>>(scores, mq, pq);

  // mixed_qk = (hs @ Wk + bk) * pooled_q
  gemm_bt<1, 1><<<dim3(8, 256), 256, 0, stream>>>(hs, WkT, bkc, mqk, pq, nullptr, flag);

  score_kernel<<<512, 256, 0, stream>>>(mqk, WkaT, bkac, maskc, scores);
  softmax_pool<<<256, 256, 0, stream>>>(scores, mqk, pk);

  // weighted = mq * pooled_k
  weighted_kernel<<<16384, 256, 0, stream>>>(mq, pk, mqk);

  // out = weighted @ Wt + bt + mixed_q
  gemm_bt<2, 0><<<dim3(8, 256), 256, 0, stream>>>(mqk, WtT, btc, d_out, nullptr, mq, flag);
}

// Round 3
// 635.830 us; speedup vs baseline: 1.2617x; 1.2617x over previous
//
#include <hip/hip_runtime.h>
#include <hip/hip_bf16.h>
#include <stdint.h>

#define D_ 1024
#define H_ 16
#define DH_ 64
#define S_ 2048
#define B_ 16
static constexpr float SCALE = 0.125f;  // 1/sqrt(64)

typedef __bf16 bf16_t;
typedef __bf16 bf16x8 __attribute__((ext_vector_type(8)));
typedef __bf16 bf16x4 __attribute__((ext_vector_type(4)));
typedef float  f32x4  __attribute__((ext_vector_type(4)));

__device__ __forceinline__ void llds16(const void* g, void* l) {
  __builtin_amdgcn_global_load_lds(
      (const __attribute__((address_space(1))) void*)g,
      (__attribute__((address_space(3))) void*)l, 16, 0, 0);
}

// ---------------------------------------------------------------------------
// hidden_states f32 -> bf16 (one pass; both big GEMMs then read bf16 A)
// ---------------------------------------------------------------------------
__global__ __launch_bounds__(256)
void f32_to_bf16(const float* __restrict__ src, bf16_t* __restrict__ dst) {
  size_t base = ((size_t)blockIdx.x * 256 + threadIdx.x) * 8;
  f32x4 a = *(const f32x4*)&src[base];
  f32x4 b = *(const f32x4*)&src[base + 4];
  bf16x8 o;
#pragma unroll
  for (int i = 0; i < 4; ++i) { o[i] = (bf16_t)a[i]; o[4 + i] = (bf16_t)b[i]; }
  *(bf16x8*)&dst[base] = o;
}

// ---------------------------------------------------------------------------
// 1024x1024 f32 -> bf16 transpose: dst[n][k] = src[k][n]
// ---------------------------------------------------------------------------
__global__ __launch_bounds__(256)
void transpose1024(const float* __restrict__ src, bf16_t* __restrict__ dst) {
  __shared__ bf16_t t[64][65];
  const int n0 = blockIdx.x * 64, k0 = blockIdx.y * 64;
  const int r = threadIdx.x >> 4, c4 = (threadIdx.x & 15) * 4;
#pragma unroll
  for (int p = 0; p < 4; ++p) {
    int row = p * 16 + r;
    f32x4 f = *(const f32x4*)&src[(size_t)(k0 + row) * 1024 + n0 + c4];
#pragma unroll
    for (int i = 0; i < 4; ++i) t[row][c4 + i] = (bf16_t)f[i];
  }
  __syncthreads();
#pragma unroll
  for (int p = 0; p < 4; ++p) {
    int row = p * 16 + r;  // n within tile
    bf16x4 v;
#pragma unroll
    for (int i = 0; i < 4; ++i) v[i] = t[c4 + i][row];
    *(bf16x4*)&dst[(size_t)(n0 + row) * 1024 + k0 + c4] = v;
  }
}

// [1024][16] f32 -> [16][1024] bf16
__global__ __launch_bounds__(256)
void transpose_small(const float* __restrict__ src, bf16_t* __restrict__ dst) {
  int k = blockIdx.x * 256 + threadIdx.x;
  if (k < 1024) {
#pragma unroll
    for (int h = 0; h < H_; ++h) dst[h * 1024 + k] = (bf16_t)src[k * H_ + h];
  }
}

// biases + mask f32 -> bf16 copies in ws
__global__ __launch_bounds__(256)
void conv_misc(const float* bq, const float* bk, const float* bt,
               const float* bqa, const float* bka, const float* mask,
               bf16_t* obq, bf16_t* obk, bf16_t* obt,
               bf16_t* obqa, bf16_t* obka, bf16_t* omask) {
  int i = blockIdx.x * 256 + threadIdx.x;
  const float* src; bf16_t* dst; int off;
  if      (i < 1024)  { src = bq;   dst = obq;   off = i; }
  else if (i < 2048)  { src = bk;   dst = obk;   off = i - 1024; }
  else if (i < 3072)  { src = bt;   dst = obt;   off = i - 2048; }
  else if (i < 3088)  { src = bqa;  dst = obqa;  off = i - 3072; }
  else if (i < 3104)  { src = bka;  dst = obka;  off = i - 3088; }
  else if (i < 35872) { src = mask; dst = omask; off = i - 3104; }
  else return;
  dst[off] = (bf16_t)src[off];
}

// ---------------------------------------------------------------------------
// GEMM: C[M][1024] = A[M][1024] @ BT[1024][1024]^T + bias (+epilogue)
// MODE 0: C = A@B + bias                      -> bf16   (mixed_q)
// MODE 1: C = (A@B + bias) * pscale[b][col]   -> bf16   (mixed_qk fused)
// MODE 2: C = A@B + bias + resid              -> f32    (final output)
// 128x128 tile, 4 waves (2x2), BK=32, global_load_lds(16B), XCD swizzle.
// m97 structure (874-912 TF verified).
// ---------------------------------------------------------------------------
template <int MODE>
__global__ __launch_bounds__(256, 2)
void gemm_bt(const bf16_t* __restrict__ A, const bf16_t* __restrict__ BT,
             const bf16_t* __restrict__ bias, void* __restrict__ Cout,
             const float* __restrict__ pscale, const bf16_t* __restrict__ resid) {
  constexpr int K = 1024, N = 1024;
  __shared__ __align__(16) bf16_t lA[128 * 32];
  __shared__ __align__(16) bf16_t lB[128 * 32];
  const int tid = threadIdx.x;
  const int lane = tid & 63, wid = tid >> 6;
  const int wr = wid >> 1, wc = wid & 1;

  // XCD-aware swizzle: nwg=2048, 2048%8==0 -> each XCD gets 256 contiguous
  // work-ids = 32 M-panels x all 8 N-tiles (A-panel fetched by one XCD only).
  const int wgid = (blockIdx.x & 7) * 256 + (blockIdx.x >> 3);
  const int m0 = (wgid >> 3) * 128;
  const int n0 = (wgid & 7) * 128;

  const int ar = lane & 15;        // fragment row/col
  const int ak = (lane >> 4) * 8;  // fragment k offset

  f32x4 acc[4][4] = {};

  for (int k0 = 0; k0 < K; k0 += 32) {
#pragma unroll
    for (int j = 0; j < 2; ++j) {
      int c = j * 256 + tid;              // chunk 0..511 (16B each)
      int row = c >> 2, kc = (c & 3) * 8;
      const bf16_t* ga = A + (size_t)(m0 + row) * K + k0 + kc;
      const bf16_t* gb = BT + (size_t)(n0 + row) * K + k0 + kc;
      bf16_t* la = lA + (size_t)(j * 256 + wid * 64) * 8;  // wave-uniform base
      bf16_t* lb = lB + (size_t)(j * 256 + wid * 64) * 8;
      llds16(ga, la);
      llds16(gb, lb);
    }
    __syncthreads();
    bf16x8 af[4], bg[4];
#pragma unroll
    for (int m = 0; m < 4; ++m)
      af[m] = *(const bf16x8*)&lA[(wr * 64 + m * 16 + ar) * 32 + ak];
#pragma unroll
    for (int n = 0; n < 4; ++n)
      bg[n] = *(const bf16x8*)&lB[(wc * 64 + n * 16 + ar) * 32 + ak];
#pragma unroll
    for (int m = 0; m < 4; ++m)
#pragma unroll
      for (int n = 0; n < 4; ++n)
        acc[m][n] = __builtin_amdgcn_mfma_f32_16x16x32_bf16(af[m], bg[n], acc[m][n], 0, 0, 0);
    __syncthreads();
  }

  const int b = m0 / S_;
#pragma unroll
  for (int m = 0; m < 4; ++m) {
#pragma unroll
    for (int n = 0; n < 4; ++n) {
      const int col = n0 + wc * 64 + n * 16 + (lane & 15);
      const int row_base = m0 + wr * 64 + m * 16 + (lane >> 4) * 4;
      const float bcol = (float)bias[col];
      const float sc = (MODE == 1) ? pscale[b * D_ + col] : 1.0f;
#pragma unroll
      for (int j = 0; j < 4; ++j) {
        const int row = row_base + j;
        float v = acc[m][n][j] + bcol;
        if (MODE == 1) v *= sc;
        if (MODE == 2) {
          v += (float)resid[(size_t)row * N + col];
          ((float*)Cout)[(size_t)row * N + col] = v;
        } else {
          ((bf16_t*)Cout)[(size_t)row * N + col] = (bf16_t)v;
        }
      }
    }
  }
}

// ---------------------------------------------------------------------------
// scores[b*H+h][s] = (X[b,s,:] . WaT[h,:] + ba[h]) * SCALE + mask[b][s]
// MFMA skinny GEMM (N=16), A direct from global (X is L3-resident).
// ---------------------------------------------------------------------------
__global__ __launch_bounds__(256)
void score_kernel(const bf16_t* __restrict__ X, const bf16_t* __restrict__ WaT,
                  const bf16_t* __restrict__ ba, const bf16_t* __restrict__ mask,
                  float* __restrict__ scores) {
  const int lane = threadIdx.x & 63, wid = threadIdx.x >> 6;
  const int m0 = blockIdx.x * 64 + wid * 16;  // global row = b*S + s
  const int ar = lane & 15, ak = (lane >> 4) * 8;
  f32x4 acc = {};
  for (int k0 = 0; k0 < D_; k0 += 32) {
    bf16x8 a = *(const bf16x8*)&X[(size_t)(m0 + ar) * D_ + k0 + ak];
    bf16x8 b = *(const bf16x8*)&WaT[(size_t)ar * D_ + k0 + ak];
    acc = __builtin_amdgcn_mfma_f32_16x16x32_bf16(a, b, acc, 0, 0, 0);
  }
  const int h = lane & 15;
  const int srow = m0 + (lane >> 4) * 4;
  const int bb = srow / S_;
  const int s0 = srow - bb * S_;
  const float bah = (float)ba[h];
  f32x4 outv;
#pragma unroll
  for (int j = 0; j < 4; ++j)
    outv[j] = (acc[j] + bah) * SCALE + (float)mask[(size_t)bb * S_ + s0 + j];
  *(f32x4*)&scores[((size_t)(bb * H_ + h)) * S_ + s0] = outv;
}

// ---------------------------------------------------------------------------
// per (b,h): softmax over scores row; pooled[b][h*64+d] = sum_s w[s]*X[b,s,h*64+d]
// ---------------------------------------------------------------------------
__global__ __launch_bounds__(256)
void softmax_pool(const float* __restrict__ scores, const bf16_t* __restrict__ X,
                  float* __restrict__ pooled) {
  __shared__ float w[S_];
  __shared__ float red[4][64];
  __shared__ float rA[4], rB[4];
  const int tid = threadIdx.x, lane = tid & 63, wid = tid >> 6;
  const int bh = blockIdx.x, b = bh >> 4, h = bh & 15;
  const float* srow = scores + (size_t)bh * S_;

  float mx = -1e30f;
  for (int i = tid; i < S_; i += 256) { float v = srow[i]; w[i] = v; mx = fmaxf(mx, v); }
#pragma unroll
  for (int o = 32; o; o >>= 1) mx = fmaxf(mx, __shfl_xor(mx, o));
  if (lane == 0) rA[wid] = mx;
  __syncthreads();
  mx = fmaxf(fmaxf(rA[0], rA[1]), fmaxf(rA[2], rA[3]));

  float sum = 0.f;
  for (int i = tid; i < S_; i += 256) { float p = __expf(w[i] - mx); w[i] = p; sum += p; }
#pragma unroll
  for (int o = 32; o; o >>= 1) sum += __shfl_xor(sum, o);
  if (lane == 0) rB[wid] = sum;
  __syncthreads();  // also orders w[] writes before pooling reads
  sum = rB[0] + rB[1] + rB[2] + rB[3];
  const float inv = 1.0f / sum;

  float accv = 0.f;
  const bf16_t* Xb = X + (size_t)b * S_ * D_ + h * DH_ + lane;  // lane = d
  for (int s = wid; s < S_; s += 4) accv += w[s] * (float)Xb[(size_t)s * D_];
  red[wid][lane] = accv;
  __syncthreads();
  if (tid < 64) {
    float r = (red[0][tid] + red[1][tid] + red[2][tid] + red[3][tid]) * inv;
    pooled[(size_t)b * D_ + h * DH_ + tid] = r;
  }
}

// ---------------------------------------------------------------------------
// weighted[b,s,d] = mq[b,s,d] * pk[b][d]  (into dead wtd buffer)
// ---------------------------------------------------------------------------
__global__ __launch_bounds__(256)
void weighted_kernel(const bf16_t* __restrict__ mq, const float* __restrict__ pk,
                     bf16_t* __restrict__ out) {
  size_t idx = ((size_t)blockIdx.x * 256 + threadIdx.x) * 8;
  int d0 = (int)(idx & (D_ - 1));
  int b = (int)(idx >> 21);  // S_*D_ = 2^21
  bf16x8 v = *(const bf16x8*)&mq[idx];
  const float* pkb = pk + (size_t)b * D_ + d0;
  bf16x8 o;
#pragma unroll
  for (int i = 0; i < 8; ++i) o[i] = (bf16_t)((float)v[i] * pkb[i]);
  *(bf16x8*)&out[idx] = o;
}

// ---------------------------------------------------------------------------
extern "C" void kernel_launch(void* const* d_in, const int* in_sizes, int n_in,
                              void* d_out, int out_size, void* d_ws, size_t ws_size,
                              hipStream_t stream) {
  const float* hs   = (const float*)d_in[0];
  const float* mask = (const float*)d_in[1];
  const float* Wq   = (const float*)d_in[2];
  const float* bq   = (const float*)d_in[3];
  const float* Wqa  = (const float*)d_in[4];
  const float* bqa  = (const float*)d_in[5];
  const float* Wk   = (const float*)d_in[6];
  const float* bk   = (const float*)d_in[7];
  const float* Wka  = (const float*)d_in[8];
  const float* bka  = (const float*)d_in[9];
  const float* Wt   = (const float*)d_in[10];
  const float* bt   = (const float*)d_in[11];

  char* ws = (char*)d_ws;
  float*  pq    = (float*)(ws + (64u << 10));
  float*  pk    = (float*)(ws + (128u << 10));
  bf16_t* bqc   = (bf16_t*)(ws + (192u << 10));
  bf16_t* bkc   = (bf16_t*)(ws + (192u << 10) + 4096);
  bf16_t* btc   = (bf16_t*)(ws + (192u << 10) + 8192);
  bf16_t* bqac  = (bf16_t*)(ws + (192u << 10) + 12288);
  bf16_t* bkac  = (bf16_t*)(ws + (192u << 10) + 12352);
  bf16_t* maskc = (bf16_t*)(ws + (256u << 10));                 // 64 KB
  bf16_t* WqaT  = (bf16_t*)(ws + (1u << 20));                   // 32 KB
  bf16_t* WkaT  = (bf16_t*)(ws + (1u << 20) + 32768);
  bf16_t* WqT   = (bf16_t*)(ws + (2u << 20));                   // 2 MB
  bf16_t* WkT   = (bf16_t*)(ws + (4u << 20));
  bf16_t* WtT   = (bf16_t*)(ws + (6u << 20));
  bf16_t* hsb   = (bf16_t*)(ws + (8u << 20));                   // 64 MB (hs bf16)
  bf16_t* mq    = (bf16_t*)(ws + (8u << 20) + ((size_t)64 << 20));
  bf16_t* mqk   = (bf16_t*)(ws + (8u << 20) + ((size_t)128 << 20));
  bf16_t* wtd   = (bf16_t*)(ws + (8u << 20) + ((size_t)192 << 20));
  float* scores = (float*)(ws + (8u << 20) + ((size_t)256 << 20)); // 2 MB

  // prep: conversions + weight transposes
  f32_to_bf16<<<16384, 256, 0, stream>>>(hs, hsb);
  conv_misc<<<141, 256, 0, stream>>>(bq, bk, bt, bqa, bka, mask,
                                     bqc, bkc, btc, bqac, bkac, maskc);
  transpose1024<<<dim3(16, 16), 256, 0, stream>>>(Wq, WqT);
  transpose1024<<<dim3(16, 16), 256, 0, stream>>>(Wk, WkT);
  transpose1024<<<dim3(16, 16), 256, 0, stream>>>(Wt, WtT);
  transpose_small<<<4, 256, 0, stream>>>(Wqa, WqaT);
  transpose_small<<<4, 256, 0, stream>>>(Wka, WkaT);

  // mixed_q = hs @ Wq + bq
  gemm_bt<0><<<2048, 256, 0, stream>>>(hsb, WqT, bqc, mq, nullptr, nullptr);

  score_kernel<<<512, 256, 0, stream>>>(mq, WqaT, bqac, maskc, scores);
  softmax_pool<<<256, 256, 0, stream>>>(scores, mq, pq);

  // mixed_qk = (hs @ Wk + bk) * pooled_q
  gemm_bt<1><<<2048, 256, 0, stream>>>(hsb, WkT, bkc, mqk, pq, nullptr);

  score_kernel<<<512, 256, 0, stream>>>(mqk, WkaT, bkac, maskc, scores);
  softmax_pool<<<256, 256, 0, stream>>>(scores, mqk, pk);

  // weighted = mq * pooled_k
  weighted_kernel<<<16384, 256, 0, stream>>>(mq, pk, wtd);

  // out = weighted @ Wt + bt + mixed_q   (f32 out)
  gemm_bt<2><<<2048, 256, 0, stream>>>(wtd, WtT, btc, d_out, nullptr, mq);
}

// Round 4
// 422.030 us; speedup vs baseline: 1.9008x; 1.5066x over previous
//
#include <hip/hip_runtime.h>
#include <hip/hip_bf16.h>
#include <stdint.h>

#define D_ 1024
#define H_ 16
#define DH_ 64
#define S_ 2048
#define B_ 16
static constexpr float SCALE = 0.125f;  // 1/sqrt(64)

typedef __bf16 bf16_t;
typedef __bf16 bf16x8 __attribute__((ext_vector_type(8)));
typedef __bf16 bf16x4 __attribute__((ext_vector_type(4)));
typedef float  f32x4  __attribute__((ext_vector_type(4)));

__device__ __forceinline__ void llds16(const void* g, void* l) {
  __builtin_amdgcn_global_load_lds(
      (const __attribute__((address_space(1))) void*)g,
      (__attribute__((address_space(3))) void*)l, 16, 0, 0);
}

// ---------------------------------------------------------------------------
// hidden_states f32 -> bf16 (one pass; both big GEMMs then read bf16 A)
// ---------------------------------------------------------------------------
__global__ __launch_bounds__(256)
void f32_to_bf16(const float* __restrict__ src, bf16_t* __restrict__ dst) {
  size_t base = ((size_t)blockIdx.x * 256 + threadIdx.x) * 8;
  f32x4 a = *(const f32x4*)&src[base];
  f32x4 b = *(const f32x4*)&src[base + 4];
  bf16x8 o;
#pragma unroll
  for (int i = 0; i < 4; ++i) { o[i] = (bf16_t)a[i]; o[4 + i] = (bf16_t)b[i]; }
  *(bf16x8*)&dst[base] = o;
}

// ---------------------------------------------------------------------------
// 1024x1024 f32 -> bf16 transpose: dst[n][k] = src[k][n]
// ---------------------------------------------------------------------------
__global__ __launch_bounds__(256)
void transpose1024(const float* __restrict__ src, bf16_t* __restrict__ dst) {
  __shared__ bf16_t t[64][65];
  const int n0 = blockIdx.x * 64, k0 = blockIdx.y * 64;
  const int r = threadIdx.x >> 4, c4 = (threadIdx.x & 15) * 4;
#pragma unroll
  for (int p = 0; p < 4; ++p) {
    int row = p * 16 + r;
    f32x4 f = *(const f32x4*)&src[(size_t)(k0 + row) * 1024 + n0 + c4];
#pragma unroll
    for (int i = 0; i < 4; ++i) t[row][c4 + i] = (bf16_t)f[i];
  }
  __syncthreads();
#pragma unroll
  for (int p = 0; p < 4; ++p) {
    int row = p * 16 + r;  // n within tile
    bf16x4 v;
#pragma unroll
    for (int i = 0; i < 4; ++i) v[i] = t[c4 + i][row];
    *(bf16x4*)&dst[(size_t)(n0 + row) * 1024 + k0 + c4] = v;
  }
}

// [1024][16] f32 -> [16][1024] bf16
__global__ __launch_bounds__(256)
void transpose_small(const float* __restrict__ src, bf16_t* __restrict__ dst) {
  int k = blockIdx.x * 256 + threadIdx.x;
  if (k < 1024) {
#pragma unroll
    for (int h = 0; h < H_; ++h) dst[h * 1024 + k] = (bf16_t)src[k * H_ + h];
  }
}

// biases + mask f32 -> bf16 copies in ws
__global__ __launch_bounds__(256)
void conv_misc(const float* bq, const float* bk, const float* bt,
               const float* bqa, const float* bka, const float* mask,
               bf16_t* obq, bf16_t* obk, bf16_t* obt,
               bf16_t* obqa, bf16_t* obka, bf16_t* omask) {
  int i = blockIdx.x * 256 + threadIdx.x;
  const float* src; bf16_t* dst; int off;
  if      (i < 1024)  { src = bq;   dst = obq;   off = i; }
  else if (i < 2048)  { src = bk;   dst = obk;   off = i - 1024; }
  else if (i < 3072)  { src = bt;   dst = obt;   off = i - 2048; }
  else if (i < 3088)  { src = bqa;  dst = obqa;  off = i - 3072; }
  else if (i < 3104)  { src = bka;  dst = obka;  off = i - 3088; }
  else if (i < 35872) { src = mask; dst = omask; off = i - 3104; }
  else return;
  dst[off] = (bf16_t)src[off];
}

// ---------------------------------------------------------------------------
// GEMM: C[M][1024] = A[M][1024] @ BT[1024][1024]^T + bias (+epilogue)
// MODE 0: -> bf16 (mixed_q); MODE 1: *pscale -> bf16 (mixed_qk);
// MODE 2: +resid -> f32 (final output)
// 128x128 tile, 4 waves, BK=32, global_load_lds(16B), XCD swizzle (m97).
// ---------------------------------------------------------------------------
template <int MODE>
__global__ __launch_bounds__(256, 2)
void gemm_bt(const bf16_t* __restrict__ A, const bf16_t* __restrict__ BT,
             const bf16_t* __restrict__ bias, void* __restrict__ Cout,
             const float* __restrict__ pscale, const bf16_t* __restrict__ resid) {
  constexpr int K = 1024, N = 1024;
  __shared__ __align__(16) bf16_t lA[128 * 32];
  __shared__ __align__(16) bf16_t lB[128 * 32];
  const int tid = threadIdx.x;
  const int lane = tid & 63, wid = tid >> 6;
  const int wr = wid >> 1, wc = wid & 1;

  const int wgid = (blockIdx.x & 7) * 256 + (blockIdx.x >> 3);
  const int m0 = (wgid >> 3) * 128;
  const int n0 = (wgid & 7) * 128;

  const int ar = lane & 15;
  const int ak = (lane >> 4) * 8;

  f32x4 acc[4][4] = {};

  for (int k0 = 0; k0 < K; k0 += 32) {
#pragma unroll
    for (int j = 0; j < 2; ++j) {
      int c = j * 256 + tid;
      int row = c >> 2, kc = (c & 3) * 8;
      const bf16_t* ga = A + (size_t)(m0 + row) * K + k0 + kc;
      const bf16_t* gb = BT + (size_t)(n0 + row) * K + k0 + kc;
      bf16_t* la = lA + (size_t)(j * 256 + wid * 64) * 8;
      bf16_t* lb = lB + (size_t)(j * 256 + wid * 64) * 8;
      llds16(ga, la);
      llds16(gb, lb);
    }
    __syncthreads();
    bf16x8 af[4], bg[4];
#pragma unroll
    for (int m = 0; m < 4; ++m)
      af[m] = *(const bf16x8*)&lA[(wr * 64 + m * 16 + ar) * 32 + ak];
#pragma unroll
    for (int n = 0; n < 4; ++n)
      bg[n] = *(const bf16x8*)&lB[(wc * 64 + n * 16 + ar) * 32 + ak];
#pragma unroll
    for (int m = 0; m < 4; ++m)
#pragma unroll
      for (int n = 0; n < 4; ++n)
        acc[m][n] = __builtin_amdgcn_mfma_f32_16x16x32_bf16(af[m], bg[n], acc[m][n], 0, 0, 0);
    __syncthreads();
  }

  const int b = m0 / S_;
#pragma unroll
  for (int m = 0; m < 4; ++m) {
#pragma unroll
    for (int n = 0; n < 4; ++n) {
      const int col = n0 + wc * 64 + n * 16 + (lane & 15);
      const int row_base = m0 + wr * 64 + m * 16 + (lane >> 4) * 4;
      const float bcol = (float)bias[col];
      const float sc = (MODE == 1) ? pscale[b * D_ + col] : 1.0f;
#pragma unroll
      for (int j = 0; j < 4; ++j) {
        const int row = row_base + j;
        float v = acc[m][n][j] + bcol;
        if (MODE == 1) v *= sc;
        if (MODE == 2) {
          v += (float)resid[(size_t)row * N + col];
          ((float*)Cout)[(size_t)row * N + col] = v;
        } else {
          ((bf16_t*)Cout)[(size_t)row * N + col] = (bf16_t)v;
        }
      }
    }
  }
}

// ---------------------------------------------------------------------------
// scores[b*H+h][s] = (X[b,s,:] . WaT[h,:] + ba[h]) * SCALE + mask[b][s]
// ---------------------------------------------------------------------------
__global__ __launch_bounds__(256)
void score_kernel(const bf16_t* __restrict__ X, const bf16_t* __restrict__ WaT,
                  const bf16_t* __restrict__ ba, const bf16_t* __restrict__ mask,
                  float* __restrict__ scores) {
  const int lane = threadIdx.x & 63, wid = threadIdx.x >> 6;
  const int m0 = blockIdx.x * 64 + wid * 16;
  const int ar = lane & 15, ak = (lane >> 4) * 8;
  f32x4 acc = {};
  for (int k0 = 0; k0 < D_; k0 += 32) {
    bf16x8 a = *(const bf16x8*)&X[(size_t)(m0 + ar) * D_ + k0 + ak];
    bf16x8 b = *(const bf16x8*)&WaT[(size_t)ar * D_ + k0 + ak];
    acc = __builtin_amdgcn_mfma_f32_16x16x32_bf16(a, b, acc, 0, 0, 0);
  }
  const int h = lane & 15;
  const int srow = m0 + (lane >> 4) * 4;
  const int bb = srow / S_;
  const int s0 = srow - bb * S_;
  const float bah = (float)ba[h];
  f32x4 outv;
#pragma unroll
  for (int j = 0; j < 4; ++j)
    outv[j] = (acc[j] + bah) * SCALE + (float)mask[(size_t)bb * S_ + s0 + j];
  *(f32x4*)&scores[((size_t)(bb * H_ + h)) * S_ + s0] = outv;
}

// ---------------------------------------------------------------------------
// softmax over each scores row -> normalized weights (row in registers)
// ---------------------------------------------------------------------------
__global__ __launch_bounds__(256)
void softmax_rows(const float* __restrict__ scores, float* __restrict__ wout) {
  __shared__ float rA[4], rB[4];
  const int tid = threadIdx.x, lane = tid & 63, wid = tid >> 6;
  const float* srow = scores + (size_t)blockIdx.x * S_;
  float* wrow = wout + (size_t)blockIdx.x * S_;
  f32x4 v0 = *(const f32x4*)&srow[tid * 4];
  f32x4 v1 = *(const f32x4*)&srow[1024 + tid * 4];
  float mx = fmaxf(fmaxf(fmaxf(v0[0], v0[1]), fmaxf(v0[2], v0[3])),
                   fmaxf(fmaxf(v1[0], v1[1]), fmaxf(v1[2], v1[3])));
#pragma unroll
  for (int o = 32; o; o >>= 1) mx = fmaxf(mx, __shfl_xor(mx, o));
  if (lane == 0) rA[wid] = mx;
  __syncthreads();
  mx = fmaxf(fmaxf(rA[0], rA[1]), fmaxf(rA[2], rA[3]));
  float sum = 0.f;
#pragma unroll
  for (int i = 0; i < 4; ++i) { v0[i] = __expf(v0[i] - mx); sum += v0[i]; }
#pragma unroll
  for (int i = 0; i < 4; ++i) { v1[i] = __expf(v1[i] - mx); sum += v1[i]; }
#pragma unroll
  for (int o = 32; o; o >>= 1) sum += __shfl_xor(sum, o);
  if (lane == 0) rB[wid] = sum;
  __syncthreads();
  sum = rB[0] + rB[1] + rB[2] + rB[3];
  const float inv = 1.0f / sum;
#pragma unroll
  for (int i = 0; i < 4; ++i) { v0[i] *= inv; v1[i] *= inv; }
  *(f32x4*)&wrow[tid * 4] = v0;
  *(f32x4*)&wrow[1024 + tid * 4] = v1;
}

// ---------------------------------------------------------------------------
// pool partials: block (chunk, b): partial[chunk][b][d] =
//   sum_{s in chunk (32 rows)} w[b, d>>6][s] * X[b,s,d]
// coalesced bf16x8 loads, per-thread f32 accum, LDS combine of 2 row-parities.
// ---------------------------------------------------------------------------
__global__ __launch_bounds__(256)
void pool_partial(const bf16_t* __restrict__ X, const float* __restrict__ w,
                  float* __restrict__ partials) {
  __shared__ float sm[2][1024];
  const int tid = threadIdx.x;
  const int chunk = blockIdx.x, b = blockIdx.y;  // 64 chunks x 32 rows
  const int s0 = chunk * 32;
  const int dc = (tid & 127) * 8;
  const int sp = tid >> 7;
  const int h = dc >> 6;
  const float* wrow = w + ((size_t)b * H_ + h) * S_ + s0;
  const bf16_t* Xb = X + ((size_t)b * S_ + s0) * D_ + dc;
  float acc[8] = {};
  for (int s = sp; s < 32; s += 2) {
    bf16x8 xv = *(const bf16x8*)&Xb[(size_t)s * D_];
    float wt = wrow[s];
#pragma unroll
    for (int j = 0; j < 8; ++j) acc[j] += wt * (float)xv[j];
  }
#pragma unroll
  for (int j = 0; j < 8; ++j) sm[sp][dc + j] = acc[j];
  __syncthreads();
  const int d0 = tid * 4;
  f32x4 r;
#pragma unroll
  for (int j = 0; j < 4; ++j) r[j] = sm[0][d0 + j] + sm[1][d0 + j];
  *(f32x4*)&partials[((size_t)chunk * B_ + b) * D_ + d0] = r;
}

// pooled[b*D+d] = sum_{c<64} partials[c][b][d]  (fixed order, deterministic)
__global__ __launch_bounds__(256)
void pool_reduce(const float* __restrict__ partials, float* __restrict__ pooled) {
  const int idx = blockIdx.x * 256 + threadIdx.x;  // 0..16383 = b*D+d
  float s = 0.f;
#pragma unroll 8
  for (int c = 0; c < 64; ++c) s += partials[(size_t)c * (B_ * D_) + idx];
  pooled[idx] = s;
}

// ---------------------------------------------------------------------------
// weighted[b,s,d] = mq[b,s,d] * pk[b][d]  (into dead wtd buffer)
// ---------------------------------------------------------------------------
__global__ __launch_bounds__(256)
void weighted_kernel(const bf16_t* __restrict__ mq, const float* __restrict__ pk,
                     bf16_t* __restrict__ out) {
  size_t idx = ((size_t)blockIdx.x * 256 + threadIdx.x) * 8;
  int d0 = (int)(idx & (D_ - 1));
  int b = (int)(idx >> 21);
  bf16x8 v = *(const bf16x8*)&mq[idx];
  const float* pkb = pk + (size_t)b * D_ + d0;
  bf16x8 o;
#pragma unroll
  for (int i = 0; i < 8; ++i) o[i] = (bf16_t)((float)v[i] * pkb[i]);
  *(bf16x8*)&out[idx] = o;
}

// ---------------------------------------------------------------------------
extern "C" void kernel_launch(void* const* d_in, const int* in_sizes, int n_in,
                              void* d_out, int out_size, void* d_ws, size_t ws_size,
                              hipStream_t stream) {
  const float* hs   = (const float*)d_in[0];
  const float* mask = (const float*)d_in[1];
  const float* Wq   = (const float*)d_in[2];
  const float* bq   = (const float*)d_in[3];
  const float* Wqa  = (const float*)d_in[4];
  const float* bqa  = (const float*)d_in[5];
  const float* Wk   = (const float*)d_in[6];
  const float* bk   = (const float*)d_in[7];
  const float* Wka  = (const float*)d_in[8];
  const float* bka  = (const float*)d_in[9];
  const float* Wt   = (const float*)d_in[10];
  const float* bt   = (const float*)d_in[11];

  char* ws = (char*)d_ws;
  float*  pq    = (float*)(ws + (64u << 10));
  float*  pk    = (float*)(ws + (128u << 10));
  bf16_t* bqc   = (bf16_t*)(ws + (192u << 10));
  bf16_t* bkc   = (bf16_t*)(ws + (192u << 10) + 4096);
  bf16_t* btc   = (bf16_t*)(ws + (192u << 10) + 8192);
  bf16_t* bqac  = (bf16_t*)(ws + (192u << 10) + 12288);
  bf16_t* bkac  = (bf16_t*)(ws + (192u << 10) + 12352);
  bf16_t* maskc = (bf16_t*)(ws + (256u << 10));
  bf16_t* WqaT  = (bf16_t*)(ws + (1u << 20));
  bf16_t* WkaT  = (bf16_t*)(ws + (1u << 20) + 32768);
  bf16_t* WqT   = (bf16_t*)(ws + (2u << 20));
  bf16_t* WkT   = (bf16_t*)(ws + (4u << 20));
  bf16_t* WtT   = (bf16_t*)(ws + (6u << 20));
  bf16_t* hsb   = (bf16_t*)(ws + (8u << 20));
  bf16_t* mq    = (bf16_t*)(ws + (8u << 20) + ((size_t)64 << 20));
  bf16_t* mqk   = (bf16_t*)(ws + (8u << 20) + ((size_t)128 << 20));
  bf16_t* wtd   = (bf16_t*)(ws + (8u << 20) + ((size_t)192 << 20));
  float* scores = (float*)(ws + (8u << 20) + ((size_t)256 << 20));   // 2 MB
  float* wsm    = (float*)(ws + (8u << 20) + ((size_t)258 << 20));   // 2 MB
  float* parts  = (float*)(ws + (8u << 20) + ((size_t)260 << 20));   // 4 MB

  // prep
  f32_to_bf16<<<16384, 256, 0, stream>>>(hs, hsb);
  conv_misc<<<141, 256, 0, stream>>>(bq, bk, bt, bqa, bka, mask,
                                     bqc, bkc, btc, bqac, bkac, maskc);
  transpose1024<<<dim3(16, 16), 256, 0, stream>>>(Wq, WqT);
  transpose1024<<<dim3(16, 16), 256, 0, stream>>>(Wk, WkT);
  transpose1024<<<dim3(16, 16), 256, 0, stream>>>(Wt, WtT);
  transpose_small<<<4, 256, 0, stream>>>(Wqa, WqaT);
  transpose_small<<<4, 256, 0, stream>>>(Wka, WkaT);

  // mixed_q = hs @ Wq + bq
  gemm_bt<0><<<2048, 256, 0, stream>>>(hsb, WqT, bqc, mq, nullptr, nullptr);

  score_kernel<<<512, 256, 0, stream>>>(mq, WqaT, bqac, maskc, scores);
  softmax_rows<<<256, 256, 0, stream>>>(scores, wsm);
  pool_partial<<<dim3(64, 16), 256, 0, stream>>>(mq, wsm, parts);
  pool_reduce<<<64, 256, 0, stream>>>(parts, pq);

  // mixed_qk = (hs @ Wk + bk) * pooled_q
  gemm_bt<1><<<2048, 256, 0, stream>>>(hsb, WkT, bkc, mqk, pq, nullptr);

  score_kernel<<<512, 256, 0, stream>>>(mqk, WkaT, bkac, maskc, scores);
  softmax_rows<<<256, 256, 0, stream>>>(scores, wsm);
  pool_partial<<<dim3(64, 16), 256, 0, stream>>>(mqk, wsm, parts);
  pool_reduce<<<64, 256, 0, stream>>>(parts, pk);

  // weighted = mq * pooled_k
  weighted_kernel<<<16384, 256, 0, stream>>>(mq, pk, wtd);

  // out = weighted @ Wt + bt + mixed_q   (f32 out)
  gemm_bt<2><<<2048, 256, 0, stream>>>(wtd, WtT, btc, d_out, nullptr, mq);
}